// Round 1
// 1017.329 us; speedup vs baseline: 1.1847x; 1.1847x over previous
//
#include <hip/hip_runtime.h>

// GAT: N=100000 E=1600000 NFEAT=256 NHID=64 NHEADS=4 NCLASS=40 (hardcoded dims).
// r9 (1205us): k_agg1v gather-BW bound (804MB fetch, 100MB x-write, 4TB/s).
// r10: structural fusions, no numerics change:
//   - s1 fused into gemm1 epilogue (kills k_s1, -102MB Wh1 re-read)
//   - gemm2 fused into aggregation (k_agg1g, 8 nodes/block, Wo in LDS):
//     x never materializes (-204MB round trip), tier logic removed
//   - att2 fused into layer-2 aggregate (k_l2): att recomputed inline
// All f32 throughout (tier A semantics). absmax expected unchanged 0.015625.

#define ALPHA 0.2f
constexpr int N_ = 100000;
constexpr int E_ = 1600000;
constexpr long OUTEL = (long)N_ * 40;

__global__ void k_sent(float* out, long n, float v) {
    long i = blockIdx.x * 256L + threadIdx.x;
    if (i < n) out[i] = v;
}

// ---------------- CSR build ----------------

__global__ void k_zero(int* p, int n) {
    int i = blockIdx.x * 256 + threadIdx.x;
    if (i < n) p[i] = 0;
}

__global__ void k_count(const int* __restrict__ dst, int* __restrict__ deg) {
    int e = blockIdx.x * 256 + threadIdx.x;
    if (e < E_) {
        int d = dst[e];
        if ((unsigned)d < (unsigned)N_) atomicAdd(&deg[d], 1);
    }
}

__global__ void k_partial(const int* __restrict__ deg, int* __restrict__ part) {
    __shared__ int sd[256];
    int b = blockIdx.x, t = threadIdx.x;
    int base = b * 1024;
    int s = 0;
    for (int i = 0; i < 4; i++) {
        int idx = base + t * 4 + i;
        if (idx < N_) s += deg[idx];
    }
    sd[t] = s;
    __syncthreads();
    for (int o = 128; o; o >>= 1) {
        if (t < o) sd[t] += sd[t + o];
        __syncthreads();
    }
    if (t == 0) part[b] = sd[0];
}

__global__ void k_scan_part(int* part, int nchunks, int* rowptr) {
    if (threadIdx.x == 0 && blockIdx.x == 0) {
        int run = 0;
        for (int b = 0; b < nchunks; b++) {
            int v = part[b];
            part[b] = run;
            run += v;
        }
        rowptr[N_] = run;
    }
}

__global__ void k_scan_final(const int* __restrict__ deg, const int* __restrict__ part,
                             int* __restrict__ rowptr, int* __restrict__ cursor) {
    __shared__ int sd[256];
    int b = blockIdx.x, t = threadIdx.x;
    int base = b * 1024;
    int v[4];
    int s = 0;
    for (int i = 0; i < 4; i++) {
        int idx = base + t * 4 + i;
        v[i] = (idx < N_) ? deg[idx] : 0;
        s += v[i];
    }
    sd[t] = s;
    __syncthreads();
    for (int o = 1; o < 256; o <<= 1) {
        int add = (t >= o) ? sd[t - o] : 0;
        __syncthreads();
        sd[t] += add;
        __syncthreads();
    }
    int off0 = part[b] + (sd[t] - s);
    for (int i = 0; i < 4; i++) {
        int idx = base + t * 4 + i;
        if (idx < N_) {
            rowptr[idx] = off0;
            cursor[idx] = off0;
            off0 += v[i];
        }
    }
}

__global__ void k_fill(const int* __restrict__ src, const int* __restrict__ dst,
                       int* __restrict__ cursor, int* __restrict__ csr) {
    int e = blockIdx.x * 256 + threadIdx.x;
    if (e < E_) {
        int d = dst[e];
        if ((unsigned)d < (unsigned)N_) {
            int p = atomicAdd(&cursor[d], 1);
            if ((unsigned)p < (unsigned)E_) csr[p] = src[e];
        }
    }
}

// ---------------- GEMM1: Wh1[n][head*64+f] = h @ W_heads[head] (f32)
//                  + fused s1 scores (s1s/s1d) from the in-register tile ----------------

__global__ __launch_bounds__(256) void k_gemm1(const float* __restrict__ h,
                                               const float* __restrict__ Whd,
                                               const float* __restrict__ ah,
                                               float* __restrict__ Wh1,
                                               float* __restrict__ s1s,
                                               float* __restrict__ s1d) {
    __shared__ float AsT[32][68];
    __shared__ float Bs[32][64];
    int row0 = blockIdx.x * 64;
    int head = blockIdx.y;
    const float* B = Whd + head * 16384;
    int t = threadIdx.x;
    int tr = (t >> 4) << 2;
    int tc = (t & 15) << 2;
    float acc[4][4] = {};

    for (int k0 = 0; k0 < 256; k0 += 32) {
#pragma unroll
        for (int u = 0; u < 2; u++) {
            int j = u * 256 + t;
            int r = j >> 3;
            int q = (j & 7) << 2;
            int gr = row0 + r;
            float4 v = make_float4(0.f, 0.f, 0.f, 0.f);
            if (gr < N_) v = *(const float4*)(h + (size_t)gr * 256 + k0 + q);
            AsT[q][r] = v.x; AsT[q + 1][r] = v.y; AsT[q + 2][r] = v.z; AsT[q + 3][r] = v.w;
        }
#pragma unroll
        for (int u = 0; u < 2; u++) {
            int j = u * 256 + t;
            int r = j >> 4;
            int q = (j & 15) << 2;
            *(float4*)(&Bs[r][q]) = *(const float4*)(B + (size_t)(k0 + r) * 64 + q);
        }
        __syncthreads();
#pragma unroll
        for (int kk = 0; kk < 32; kk++) {
            float4 av = *(const float4*)(&AsT[kk][tr]);
            float4 bv = *(const float4*)(&Bs[kk][tc]);
            acc[0][0] += av.x * bv.x; acc[0][1] += av.x * bv.y; acc[0][2] += av.x * bv.z; acc[0][3] += av.x * bv.w;
            acc[1][0] += av.y * bv.x; acc[1][1] += av.y * bv.y; acc[1][2] += av.y * bv.z; acc[1][3] += av.y * bv.w;
            acc[2][0] += av.z * bv.x; acc[2][1] += av.z * bv.y; acc[2][2] += av.z * bv.z; acc[2][3] += av.z * bv.w;
            acc[3][0] += av.w * bv.x; acc[3][1] += av.w * bv.y; acc[3][2] += av.w * bv.z; acc[3][3] += av.w * bv.w;
        }
        __syncthreads();
    }
#pragma unroll
    for (int i = 0; i < 4; i++) {
        int gr = row0 + tr + i;
        if (gr < N_) {
            float4 o = make_float4(acc[i][0], acc[i][1], acc[i][2], acc[i][3]);
            *(float4*)(Wh1 + (size_t)gr * 256 + head * 64 + tc) = o;
        }
    }

    // fused s1: s1s[n*4+head] = dot(Wh1[n, head*64:+64], ah[head*128 : +64])
    //           s1d[n*4+head] = dot(Wh1[n, head*64:+64], ah[head*128+64 : +128])
    float as_[4], ad_[4];
#pragma unroll
    for (int j = 0; j < 4; j++) {
        as_[j] = ah[head * 128 + tc + j];
        ad_[j] = ah[head * 128 + 64 + tc + j];
    }
#pragma unroll
    for (int i = 0; i < 4; i++) {
        float ps = acc[i][0] * as_[0] + acc[i][1] * as_[1] + acc[i][2] * as_[2] + acc[i][3] * as_[3];
        float pd = acc[i][0] * ad_[0] + acc[i][1] * ad_[1] + acc[i][2] * ad_[2] + acc[i][3] * ad_[3];
        // reduce across the 16 threads (same t>>4) covering this row; they are
        // 16 consecutive lanes of one wave, so xor 8/4/2/1 stays in-group.
        for (int o = 8; o; o >>= 1) {
            ps += __shfl_xor(ps, o);
            pd += __shfl_xor(pd, o);
        }
        int gr = row0 + tr + i;
        if ((t & 15) == 0 && gr < N_) {
            s1s[gr * 4 + head] = ps;
            s1d[gr * 4 + head] = pd;
        }
    }
}

// ---------------- att1: per-node softmax -> att per (csr_pos, head) ----------------

__global__ __launch_bounds__(256) void k_att1(const int* __restrict__ rowptr, const int* __restrict__ csr,
                                              const float* __restrict__ s1s, const float* __restrict__ s1d,
                                              float* __restrict__ att1) {
    int n = blockIdx.x;
    int base = rowptr[n], deg = rowptr[n + 1] - base;
    if (deg < 0) deg = 0;
    int t = threadIdx.x;
    int w = t >> 6, lane = t & 63;
    float sdw = s1d[n * 4 + w];
    __shared__ float smx[4], sinv[4];

    float mx = -INFINITY;
    for (int i = lane; i < deg; i += 64) {
        int s = csr[base + i];
        if ((unsigned)s >= (unsigned)N_) s = 0;
        float e = s1s[s * 4 + w] + sdw;
        e = e > 0.f ? e : ALPHA * e;
        mx = fmaxf(mx, e);
    }
    for (int o = 32; o; o >>= 1) mx = fmaxf(mx, __shfl_xor(mx, o));
    float sm = 0.f;
    for (int i = lane; i < deg; i += 64) {
        int s = csr[base + i];
        if ((unsigned)s >= (unsigned)N_) s = 0;
        float e = s1s[s * 4 + w] + sdw;
        e = e > 0.f ? e : ALPHA * e;
        sm += expf(e - mx);
    }
    for (int o = 32; o; o >>= 1) sm += __shfl_xor(sm, o);
    if (lane == 0) {
        smx[w] = mx;
        sinv[w] = (deg > 0) ? 1.f / sm : 0.f;
    }
    __syncthreads();

    int m4 = deg * 4;
    for (int idx = t; idx < m4; idx += 256) {
        int i = idx >> 2, ww = idx & 3;
        int s = csr[base + i];
        if ((unsigned)s >= (unsigned)N_) s = 0;
        float e = s1s[s * 4 + ww] + s1d[n * 4 + ww];
        e = e > 0.f ? e : ALPHA * e;
        att1[(size_t)(base + i) * 4 + ww] = expf(e - smx[ww]) * sinv[ww];
    }
}

// ---------------- layer-1 aggregate + ELU + GEMM2 + s2 scores, fused.
// 8 nodes/block, 1 wave/node, float4 gather. x lives only in wave-private LDS.
// Wo (256x40 f32 = 40KB) staged once per block; single early barrier; the
// per-wave tail has no cross-wave dependency so degree imbalance doesn't couple.

__global__ __launch_bounds__(512) void k_agg1g(const int* __restrict__ rowptr, const int* __restrict__ csr,
                                               const float* __restrict__ att1, const float* __restrict__ Wh1,
                                               const float* __restrict__ Wo, const float* __restrict__ ao,
                                               float* __restrict__ Wh2,
                                               float* __restrict__ s2s, float* __restrict__ s2d) {
    __shared__ float WoS[256 * 40];   // [k][c] layout: 2-way bank alias on read (free)
    __shared__ float xs[8][256];
    int t = threadIdx.x;
#pragma unroll
    for (int u = 0; u < 5; u++) {
        int idx = (u * 512 + t) * 4;
        *(float4*)(&WoS[idx]) = *(const float4*)(&Wo[idx]);
    }
    __syncthreads();   // only WoS needs this; xs is wave-private

    int w = t >> 6, lane = t & 63;
    int n = blockIdx.x * 8 + w;         // N_ = 12500*8 exactly
    int base = rowptr[n], deg = rowptr[n + 1] - base;
    if (deg < 0) deg = 0;
    int f = lane << 2;                  // this lane's 4 features
    int hw = lane >> 4;                 // head = f>>6

    float4 acc = make_float4(0.f, 0.f, 0.f, 0.f);
    int i = 0;
    for (; i + 1 < deg; i += 2) {
        int s0 = csr[base + i], s1 = csr[base + i + 1];
        float at0 = att1[(size_t)(base + i) * 4 + hw];
        float at1 = att1[(size_t)(base + i + 1) * 4 + hw];
        if ((unsigned)s0 >= (unsigned)N_) s0 = 0;
        if ((unsigned)s1 >= (unsigned)N_) s1 = 0;
        float4 v0 = *(const float4*)(Wh1 + (size_t)s0 * 256 + f);
        float4 v1 = *(const float4*)(Wh1 + (size_t)s1 * 256 + f);
        acc.x += at0 * v0.x + at1 * v1.x;
        acc.y += at0 * v0.y + at1 * v1.y;
        acc.z += at0 * v0.z + at1 * v1.z;
        acc.w += at0 * v0.w + at1 * v1.w;
    }
    if (i < deg) {
        int s0 = csr[base + i];
        float at0 = att1[(size_t)(base + i) * 4 + hw];
        if ((unsigned)s0 >= (unsigned)N_) s0 = 0;
        float4 v0 = *(const float4*)(Wh1 + (size_t)s0 * 256 + f);
        acc.x += at0 * v0.x;
        acc.y += at0 * v0.y;
        acc.z += at0 * v0.z;
        acc.w += at0 * v0.w;
    }
    // ELU
    acc.x = acc.x > 0.f ? acc.x : (expf(acc.x) - 1.f);
    acc.y = acc.y > 0.f ? acc.y : (expf(acc.y) - 1.f);
    acc.z = acc.z > 0.f ? acc.z : (expf(acc.z) - 1.f);
    acc.w = acc.w > 0.f ? acc.w : (expf(acc.w) - 1.f);
    *(float4*)(&xs[w][f]) = acc;
    // wave-private LDS RAW: compiler inserts lgkmcnt wait; no barrier needed.

    // GEMM2 tail: lanes 0..39 compute Wh2[n][c]; xs reads are wave-uniform broadcast.
    float o = 0.f;
    if (lane < 40) {
        for (int k = 0; k < 256; k += 4) {
            float4 xk = *(const float4*)(&xs[w][k]);
            o += xk.x * WoS[k * 40 + lane] + xk.y * WoS[(k + 1) * 40 + lane] +
                 xk.z * WoS[(k + 2) * 40 + lane] + xk.w * WoS[(k + 3) * 40 + lane];
        }
        Wh2[(size_t)n * 40 + lane] = o;
    }
    float a1 = (lane < 40) ? ao[lane] : 0.f;
    float a2 = (lane < 40) ? ao[40 + lane] : 0.f;
    float r1 = o * a1, r2 = o * a2;
    for (int off = 32; off; off >>= 1) {
        r1 += __shfl_xor(r1, off);
        r2 += __shfl_xor(r2, off);
    }
    if (lane == 0) {
        s2s[n] = r1;
        s2d[n] = r2;
    }
}

// ---------------- layer-2: att2 computed inline + aggregate + log_softmax ----------------

__global__ __launch_bounds__(64) void k_l2(const int* __restrict__ rowptr, const int* __restrict__ csr,
                                           const float* __restrict__ s2s, const float* __restrict__ s2d,
                                           const float* __restrict__ Wh2, float* __restrict__ out) {
    int n = blockIdx.x;
    int base = rowptr[n], deg = rowptr[n + 1] - base;
    if (deg < 0) deg = 0;
    int lane = threadIdx.x;
    float sdw = s2d[n];

    float mx = -INFINITY;
    for (int i = lane; i < deg; i += 64) {
        int s = csr[base + i];
        if ((unsigned)s >= (unsigned)N_) s = 0;
        float e = s2s[s] + sdw;
        e = e > 0.f ? e : ALPHA * e;
        mx = fmaxf(mx, e);
    }
    for (int o = 32; o; o >>= 1) mx = fmaxf(mx, __shfl_xor(mx, o));
    float sm = 0.f;
    for (int i = lane; i < deg; i += 64) {
        int s = csr[base + i];
        if ((unsigned)s >= (unsigned)N_) s = 0;
        float e = s2s[s] + sdw;
        e = e > 0.f ? e : ALPHA * e;
        sm += expf(e - mx);
    }
    for (int o = 32; o; o >>= 1) sm += __shfl_xor(sm, o);
    float inv = (deg > 0) ? 1.f / sm : 0.f;

    float acc = 0.f;
    for (int i = 0; i < deg; i++) {
        int s = csr[base + i];
        if ((unsigned)s >= (unsigned)N_) s = 0;
        float e = s2s[s] + sdw;                 // broadcast load; redundant per lane, cheap
        e = e > 0.f ? e : ALPHA * e;
        float a = expf(e - mx) * inv;
        if (lane < 40) acc += a * Wh2[(size_t)s * 40 + lane];
    }

    float v = (lane < 40) ? acc : -INFINITY;
    float mv = v;
    for (int o = 32; o; o >>= 1) mv = fmaxf(mv, __shfl_xor(mv, o));
    float ex = (lane < 40) ? expf(acc - mv) : 0.f;
    float se = ex;
    for (int o = 32; o; o >>= 1) se += __shfl_xor(se, o);
    if (lane < 40) out[(size_t)n * 40 + lane] = acc - mv - logf(se);
}

// ---------------- host ----------------

extern "C" void kernel_launch(void* const* d_in, const int* in_sizes, int n_in,
                              void* d_out, int out_size, void* d_ws, size_t ws_size,
                              hipStream_t stream) {
    const float* h   = (const float*)d_in[0];
    const int*   ei  = (const int*)d_in[1];
    const float* Whd = (const float*)d_in[2];
    const float* ah  = (const float*)d_in[3];
    const float* Wo  = (const float*)d_in[4];
    const float* ao  = (const float*)d_in[5];
    float* out = (float*)d_out;

    const int* src = ei;
    const int* dst = ei + E_;
    const int nchunks = (N_ + 1023) / 1024;

    char* ws = (char*)d_ws;
    size_t off = 0;
    auto alloc = [&](size_t bytes) -> char* {
        size_t a = (off + 255) & ~(size_t)255;
        off = a + bytes;
        return ws + a;
    };
    int* rowptr = (int*)alloc((size_t)(N_ + 1) * 4);
    int* cursor = (int*)alloc((size_t)N_ * 4);
    int* deg    = (int*)alloc((size_t)N_ * 4);
    int* part   = (int*)alloc((size_t)(nchunks + 1) * 4);
    int* csr    = (int*)alloc((size_t)E_ * 4);
    float* s1s  = (float*)alloc((size_t)N_ * 4 * 4);
    float* s1d  = (float*)alloc((size_t)N_ * 4 * 4);
    float* Wh2  = (float*)alloc((size_t)N_ * 40 * 4);
    float* s2s  = (float*)alloc((size_t)N_ * 4);
    float* s2d  = (float*)alloc((size_t)N_ * 4);
    float* att1 = (float*)alloc((size_t)E_ * 4 * 4);   // 25.6 MB
    float* Wh1  = (float*)alloc((size_t)N_ * 256 * 4); // 102.4 MB
    size_t need = off + 256;                            // ~155 MB total

    if (ws_size < need) {
        k_sent<<<(int)((OUTEL + 255) / 256), 256, 0, stream>>>(out, OUTEL, -2.0f);
        return;
    }

    // CSR build
    k_zero<<<(N_ + 255) / 256, 256, 0, stream>>>(deg, N_);
    k_count<<<(E_ + 255) / 256, 256, 0, stream>>>(dst, deg);
    k_partial<<<nchunks, 256, 0, stream>>>(deg, part);
    k_scan_part<<<1, 64, 0, stream>>>(part, nchunks, rowptr);
    k_scan_final<<<nchunks, 256, 0, stream>>>(deg, part, rowptr, cursor);
    k_fill<<<(E_ + 255) / 256, 256, 0, stream>>>(src, dst, cursor, csr);

    // layer 1 (s1 fused into gemm1)
    dim3 g1((N_ + 63) / 64, 4);
    k_gemm1<<<g1, 256, 0, stream>>>(h, Whd, ah, Wh1, s1s, s1d);
    k_att1<<<N_, 256, 0, stream>>>(rowptr, csr, s1s, s1d, att1);

    // fused aggregate + ELU + gemm2 + s2 scores (x never materialized)
    k_agg1g<<<N_ / 8, 512, 0, stream>>>(rowptr, csr, att1, Wh1, Wo, ao, Wh2, s2s, s2d);

    // layer 2 (att2 fused into aggregate)
    k_l2<<<N_, 64, 0, stream>>>(rowptr, csr, s2s, s2d, Wh2, out);
}

// Round 2
// 965.609 us; speedup vs baseline: 1.2482x; 1.0536x over previous
//
#include <hip/hip_runtime.h>

// GAT: N=100000 E=1600000 NFEAT=256 NHID=64 NHEADS=4 NCLASS=40 (hardcoded dims).
// r10 (1017us): fused k_agg1g = 281us, occ 55% (49KB LDS, 8-node blocks recycle
// slots; WoS staged 12500x), VALU 50%, fabric 2.9TB/s (vs 4.05 unfused r9).
// r11: persistent k_agg1g (768 blocks = 3/CU, WoS staged once/block, waves loop
// ~16 nodes each), 4-edge unroll gather (2x in-flight loads), hoisted epilogue
// constants; k_l2 2-edge unroll + inv factored out. No numerics change.

#define ALPHA 0.2f
constexpr int N_ = 100000;
constexpr int E_ = 1600000;
constexpr long OUTEL = (long)N_ * 40;

__global__ void k_sent(float* out, long n, float v) {
    long i = blockIdx.x * 256L + threadIdx.x;
    if (i < n) out[i] = v;
}

// ---------------- CSR build ----------------

__global__ void k_zero(int* p, int n) {
    int i = blockIdx.x * 256 + threadIdx.x;
    if (i < n) p[i] = 0;
}

__global__ void k_count(const int* __restrict__ dst, int* __restrict__ deg) {
    int e = blockIdx.x * 256 + threadIdx.x;
    if (e < E_) {
        int d = dst[e];
        if ((unsigned)d < (unsigned)N_) atomicAdd(&deg[d], 1);
    }
}

__global__ void k_partial(const int* __restrict__ deg, int* __restrict__ part) {
    __shared__ int sd[256];
    int b = blockIdx.x, t = threadIdx.x;
    int base = b * 1024;
    int s = 0;
    for (int i = 0; i < 4; i++) {
        int idx = base + t * 4 + i;
        if (idx < N_) s += deg[idx];
    }
    sd[t] = s;
    __syncthreads();
    for (int o = 128; o; o >>= 1) {
        if (t < o) sd[t] += sd[t + o];
        __syncthreads();
    }
    if (t == 0) part[b] = sd[0];
}

__global__ void k_scan_part(int* part, int nchunks, int* rowptr) {
    if (threadIdx.x == 0 && blockIdx.x == 0) {
        int run = 0;
        for (int b = 0; b < nchunks; b++) {
            int v = part[b];
            part[b] = run;
            run += v;
        }
        rowptr[N_] = run;
    }
}

__global__ void k_scan_final(const int* __restrict__ deg, const int* __restrict__ part,
                             int* __restrict__ rowptr, int* __restrict__ cursor) {
    __shared__ int sd[256];
    int b = blockIdx.x, t = threadIdx.x;
    int base = b * 1024;
    int v[4];
    int s = 0;
    for (int i = 0; i < 4; i++) {
        int idx = base + t * 4 + i;
        v[i] = (idx < N_) ? deg[idx] : 0;
        s += v[i];
    }
    sd[t] = s;
    __syncthreads();
    for (int o = 1; o < 256; o <<= 1) {
        int add = (t >= o) ? sd[t - o] : 0;
        __syncthreads();
        sd[t] += add;
        __syncthreads();
    }
    int off0 = part[b] + (sd[t] - s);
    for (int i = 0; i < 4; i++) {
        int idx = base + t * 4 + i;
        if (idx < N_) {
            rowptr[idx] = off0;
            cursor[idx] = off0;
            off0 += v[i];
        }
    }
}

__global__ void k_fill(const int* __restrict__ src, const int* __restrict__ dst,
                       int* __restrict__ cursor, int* __restrict__ csr) {
    int e = blockIdx.x * 256 + threadIdx.x;
    if (e < E_) {
        int d = dst[e];
        if ((unsigned)d < (unsigned)N_) {
            int p = atomicAdd(&cursor[d], 1);
            if ((unsigned)p < (unsigned)E_) csr[p] = src[e];
        }
    }
}

// ---------------- GEMM1: Wh1[n][head*64+f] = h @ W_heads[head] (f32)
//                  + fused s1 scores (s1s/s1d) from the in-register tile ----------------

__global__ __launch_bounds__(256) void k_gemm1(const float* __restrict__ h,
                                               const float* __restrict__ Whd,
                                               const float* __restrict__ ah,
                                               float* __restrict__ Wh1,
                                               float* __restrict__ s1s,
                                               float* __restrict__ s1d) {
    __shared__ float AsT[32][68];
    __shared__ float Bs[32][64];
    int row0 = blockIdx.x * 64;
    int head = blockIdx.y;
    const float* B = Whd + head * 16384;
    int t = threadIdx.x;
    int tr = (t >> 4) << 2;
    int tc = (t & 15) << 2;
    float acc[4][4] = {};

    for (int k0 = 0; k0 < 256; k0 += 32) {
#pragma unroll
        for (int u = 0; u < 2; u++) {
            int j = u * 256 + t;
            int r = j >> 3;
            int q = (j & 7) << 2;
            int gr = row0 + r;
            float4 v = make_float4(0.f, 0.f, 0.f, 0.f);
            if (gr < N_) v = *(const float4*)(h + (size_t)gr * 256 + k0 + q);
            AsT[q][r] = v.x; AsT[q + 1][r] = v.y; AsT[q + 2][r] = v.z; AsT[q + 3][r] = v.w;
        }
#pragma unroll
        for (int u = 0; u < 2; u++) {
            int j = u * 256 + t;
            int r = j >> 4;
            int q = (j & 15) << 2;
            *(float4*)(&Bs[r][q]) = *(const float4*)(B + (size_t)(k0 + r) * 64 + q);
        }
        __syncthreads();
#pragma unroll
        for (int kk = 0; kk < 32; kk++) {
            float4 av = *(const float4*)(&AsT[kk][tr]);
            float4 bv = *(const float4*)(&Bs[kk][tc]);
            acc[0][0] += av.x * bv.x; acc[0][1] += av.x * bv.y; acc[0][2] += av.x * bv.z; acc[0][3] += av.x * bv.w;
            acc[1][0] += av.y * bv.x; acc[1][1] += av.y * bv.y; acc[1][2] += av.y * bv.z; acc[1][3] += av.y * bv.w;
            acc[2][0] += av.z * bv.x; acc[2][1] += av.z * bv.y; acc[2][2] += av.z * bv.z; acc[2][3] += av.z * bv.w;
            acc[3][0] += av.w * bv.x; acc[3][1] += av.w * bv.y; acc[3][2] += av.w * bv.z; acc[3][3] += av.w * bv.w;
        }
        __syncthreads();
    }
#pragma unroll
    for (int i = 0; i < 4; i++) {
        int gr = row0 + tr + i;
        if (gr < N_) {
            float4 o = make_float4(acc[i][0], acc[i][1], acc[i][2], acc[i][3]);
            *(float4*)(Wh1 + (size_t)gr * 256 + head * 64 + tc) = o;
        }
    }

    // fused s1: s1s[n*4+head] = dot(Wh1[n, head*64:+64], ah[head*128 : +64])
    //           s1d[n*4+head] = dot(Wh1[n, head*64:+64], ah[head*128+64 : +128])
    float as_[4], ad_[4];
#pragma unroll
    for (int j = 0; j < 4; j++) {
        as_[j] = ah[head * 128 + tc + j];
        ad_[j] = ah[head * 128 + 64 + tc + j];
    }
#pragma unroll
    for (int i = 0; i < 4; i++) {
        float ps = acc[i][0] * as_[0] + acc[i][1] * as_[1] + acc[i][2] * as_[2] + acc[i][3] * as_[3];
        float pd = acc[i][0] * ad_[0] + acc[i][1] * ad_[1] + acc[i][2] * ad_[2] + acc[i][3] * ad_[3];
        for (int o = 8; o; o >>= 1) {
            ps += __shfl_xor(ps, o);
            pd += __shfl_xor(pd, o);
        }
        int gr = row0 + tr + i;
        if ((t & 15) == 0 && gr < N_) {
            s1s[gr * 4 + head] = ps;
            s1d[gr * 4 + head] = pd;
        }
    }
}

// ---------------- att1: per-node softmax -> att per (csr_pos, head) ----------------

__global__ __launch_bounds__(256) void k_att1(const int* __restrict__ rowptr, const int* __restrict__ csr,
                                              const float* __restrict__ s1s, const float* __restrict__ s1d,
                                              float* __restrict__ att1) {
    int n = blockIdx.x;
    int base = rowptr[n], deg = rowptr[n + 1] - base;
    if (deg < 0) deg = 0;
    int t = threadIdx.x;
    int w = t >> 6, lane = t & 63;
    float sdw = s1d[n * 4 + w];
    __shared__ float smx[4], sinv[4];

    float mx = -INFINITY;
    for (int i = lane; i < deg; i += 64) {
        int s = csr[base + i];
        if ((unsigned)s >= (unsigned)N_) s = 0;
        float e = s1s[s * 4 + w] + sdw;
        e = e > 0.f ? e : ALPHA * e;
        mx = fmaxf(mx, e);
    }
    for (int o = 32; o; o >>= 1) mx = fmaxf(mx, __shfl_xor(mx, o));
    float sm = 0.f;
    for (int i = lane; i < deg; i += 64) {
        int s = csr[base + i];
        if ((unsigned)s >= (unsigned)N_) s = 0;
        float e = s1s[s * 4 + w] + sdw;
        e = e > 0.f ? e : ALPHA * e;
        sm += expf(e - mx);
    }
    for (int o = 32; o; o >>= 1) sm += __shfl_xor(sm, o);
    if (lane == 0) {
        smx[w] = mx;
        sinv[w] = (deg > 0) ? 1.f / sm : 0.f;
    }
    __syncthreads();

    int m4 = deg * 4;
    for (int idx = t; idx < m4; idx += 256) {
        int i = idx >> 2, ww = idx & 3;
        int s = csr[base + i];
        if ((unsigned)s >= (unsigned)N_) s = 0;
        float e = s1s[s * 4 + ww] + s1d[n * 4 + ww];
        e = e > 0.f ? e : ALPHA * e;
        att1[(size_t)(base + i) * 4 + ww] = expf(e - smx[ww]) * sinv[ww];
    }
}

// ---------------- layer-1 aggregate + ELU + GEMM2 + s2 scores, fused, PERSISTENT.
// 768 blocks (3/CU, LDS-capped), 8 waves/block, each wave loops nodes with
// stride 6144. Wo staged in LDS ONCE per block. Gather: 4-edge unroll, float4.
// x lives only in wave-private LDS.

constexpr int AGG_BLOCKS = 768;
constexpr int NODES_PER_SWEEP = AGG_BLOCKS * 8;

__global__ __launch_bounds__(512) void k_agg1g(const int* __restrict__ rowptr, const int* __restrict__ csr,
                                               const float* __restrict__ att1, const float* __restrict__ Wh1,
                                               const float* __restrict__ Wo, const float* __restrict__ ao,
                                               float* __restrict__ Wh2,
                                               float* __restrict__ s2s, float* __restrict__ s2d) {
    __shared__ float WoS[256 * 40];   // [k][c]: lanes 0..39 read consecutive -> <=2-way alias (free)
    __shared__ float xs[8][256];
    int t = threadIdx.x;
#pragma unroll
    for (int u = 0; u < 5; u++) {
        int idx = (u * 512 + t) * 4;
        *(float4*)(&WoS[idx]) = *(const float4*)(&Wo[idx]);
    }
    __syncthreads();   // once per block; xs is wave-private afterwards

    int w = t >> 6, lane = t & 63;
    int f = lane << 2;                  // this lane's 4 features
    int hw = lane >> 4;                 // head = f>>6
    float a1 = (lane < 40) ? ao[lane] : 0.f;
    float a2 = (lane < 40) ? ao[40 + lane] : 0.f;

    for (int n = blockIdx.x * 8 + w; n < N_; n += NODES_PER_SWEEP) {
        int base = rowptr[n], deg = rowptr[n + 1] - base;
        if (deg < 0) deg = 0;

        float4 acc = make_float4(0.f, 0.f, 0.f, 0.f);
        int i = 0;
        for (; i + 3 < deg; i += 4) {
            int b0 = base + i;
            int s0 = csr[b0], s1 = csr[b0 + 1], s2 = csr[b0 + 2], s3 = csr[b0 + 3];
            float at0 = att1[(size_t)b0 * 4 + hw];
            float at1 = att1[(size_t)(b0 + 1) * 4 + hw];
            float at2 = att1[(size_t)(b0 + 2) * 4 + hw];
            float at3 = att1[(size_t)(b0 + 3) * 4 + hw];
            if ((unsigned)s0 >= (unsigned)N_) s0 = 0;
            if ((unsigned)s1 >= (unsigned)N_) s1 = 0;
            if ((unsigned)s2 >= (unsigned)N_) s2 = 0;
            if ((unsigned)s3 >= (unsigned)N_) s3 = 0;
            float4 v0 = *(const float4*)(Wh1 + (size_t)s0 * 256 + f);
            float4 v1 = *(const float4*)(Wh1 + (size_t)s1 * 256 + f);
            float4 v2 = *(const float4*)(Wh1 + (size_t)s2 * 256 + f);
            float4 v3 = *(const float4*)(Wh1 + (size_t)s3 * 256 + f);
            acc.x += at0 * v0.x + at1 * v1.x + at2 * v2.x + at3 * v3.x;
            acc.y += at0 * v0.y + at1 * v1.y + at2 * v2.y + at3 * v3.y;
            acc.z += at0 * v0.z + at1 * v1.z + at2 * v2.z + at3 * v3.z;
            acc.w += at0 * v0.w + at1 * v1.w + at2 * v2.w + at3 * v3.w;
        }
        for (; i < deg; i++) {
            int s0 = csr[base + i];
            float at0 = att1[(size_t)(base + i) * 4 + hw];
            if ((unsigned)s0 >= (unsigned)N_) s0 = 0;
            float4 v0 = *(const float4*)(Wh1 + (size_t)s0 * 256 + f);
            acc.x += at0 * v0.x;
            acc.y += at0 * v0.y;
            acc.z += at0 * v0.z;
            acc.w += at0 * v0.w;
        }
        // ELU
        acc.x = acc.x > 0.f ? acc.x : (expf(acc.x) - 1.f);
        acc.y = acc.y > 0.f ? acc.y : (expf(acc.y) - 1.f);
        acc.z = acc.z > 0.f ? acc.z : (expf(acc.z) - 1.f);
        acc.w = acc.w > 0.f ? acc.w : (expf(acc.w) - 1.f);
        *(float4*)(&xs[w][f]) = acc;
        // wave-private LDS RAW: compiler inserts lgkmcnt wait; no barrier needed.

        // GEMM2 tail: lanes 0..39 compute Wh2[n][c]; xs reads are wave-uniform broadcast.
        float o = 0.f;
        if (lane < 40) {
            for (int k = 0; k < 256; k += 4) {
                float4 xk = *(const float4*)(&xs[w][k]);
                o += xk.x * WoS[k * 40 + lane] + xk.y * WoS[(k + 1) * 40 + lane] +
                     xk.z * WoS[(k + 2) * 40 + lane] + xk.w * WoS[(k + 3) * 40 + lane];
            }
            Wh2[(size_t)n * 40 + lane] = o;
        }
        float r1 = o * a1, r2 = o * a2;
        for (int off = 32; off; off >>= 1) {
            r1 += __shfl_xor(r1, off);
            r2 += __shfl_xor(r2, off);
        }
        if (lane == 0) {
            s2s[n] = r1;
            s2d[n] = r2;
        }
    }
}

// ---------------- layer-2: att2 computed inline + aggregate + log_softmax ----------------

__global__ __launch_bounds__(64) void k_l2(const int* __restrict__ rowptr, const int* __restrict__ csr,
                                           const float* __restrict__ s2s, const float* __restrict__ s2d,
                                           const float* __restrict__ Wh2, float* __restrict__ out) {
    int n = blockIdx.x;
    int base = rowptr[n], deg = rowptr[n + 1] - base;
    if (deg < 0) deg = 0;
    int lane = threadIdx.x;
    float sdw = s2d[n];

    float mx = -INFINITY;
    for (int i = lane; i < deg; i += 64) {
        int s = csr[base + i];
        if ((unsigned)s >= (unsigned)N_) s = 0;
        float e = s2s[s] + sdw;
        e = e > 0.f ? e : ALPHA * e;
        mx = fmaxf(mx, e);
    }
    for (int o = 32; o; o >>= 1) mx = fmaxf(mx, __shfl_xor(mx, o));
    float sm = 0.f;
    for (int i = lane; i < deg; i += 64) {
        int s = csr[base + i];
        if ((unsigned)s >= (unsigned)N_) s = 0;
        float e = s2s[s] + sdw;
        e = e > 0.f ? e : ALPHA * e;
        sm += expf(e - mx);
    }
    for (int o = 32; o; o >>= 1) sm += __shfl_xor(sm, o);
    float inv = (deg > 0) ? 1.f / sm : 0.f;

    // aggregate: 2-edge unroll, dual accumulators, inv factored out (1-ulp class change)
    float acc0 = 0.f, acc1 = 0.f;
    int i = 0;
    for (; i + 1 < deg; i += 2) {
        int s0 = csr[base + i], s1 = csr[base + i + 1];
        if ((unsigned)s0 >= (unsigned)N_) s0 = 0;
        if ((unsigned)s1 >= (unsigned)N_) s1 = 0;
        float e0 = s2s[s0] + sdw;
        float e1 = s2s[s1] + sdw;
        e0 = e0 > 0.f ? e0 : ALPHA * e0;
        e1 = e1 > 0.f ? e1 : ALPHA * e1;
        float a0 = expf(e0 - mx);
        float a1 = expf(e1 - mx);
        if (lane < 40) {
            acc0 += a0 * Wh2[(size_t)s0 * 40 + lane];
            acc1 += a1 * Wh2[(size_t)s1 * 40 + lane];
        }
    }
    if (i < deg) {
        int s0 = csr[base + i];
        if ((unsigned)s0 >= (unsigned)N_) s0 = 0;
        float e0 = s2s[s0] + sdw;
        e0 = e0 > 0.f ? e0 : ALPHA * e0;
        float a0 = expf(e0 - mx);
        if (lane < 40) acc0 += a0 * Wh2[(size_t)s0 * 40 + lane];
    }
    float acc = (acc0 + acc1) * inv;

    float v = (lane < 40) ? acc : -INFINITY;
    float mv = v;
    for (int o = 32; o; o >>= 1) mv = fmaxf(mv, __shfl_xor(mv, o));
    float ex = (lane < 40) ? expf(acc - mv) : 0.f;
    float se = ex;
    for (int o = 32; o; o >>= 1) se += __shfl_xor(se, o);
    if (lane < 40) out[(size_t)n * 40 + lane] = acc - mv - logf(se);
}

// ---------------- host ----------------

extern "C" void kernel_launch(void* const* d_in, const int* in_sizes, int n_in,
                              void* d_out, int out_size, void* d_ws, size_t ws_size,
                              hipStream_t stream) {
    const float* h   = (const float*)d_in[0];
    const int*   ei  = (const int*)d_in[1];
    const float* Whd = (const float*)d_in[2];
    const float* ah  = (const float*)d_in[3];
    const float* Wo  = (const float*)d_in[4];
    const float* ao  = (const float*)d_in[5];
    float* out = (float*)d_out;

    const int* src = ei;
    const int* dst = ei + E_;
    const int nchunks = (N_ + 1023) / 1024;

    char* ws = (char*)d_ws;
    size_t off = 0;
    auto alloc = [&](size_t bytes) -> char* {
        size_t a = (off + 255) & ~(size_t)255;
        off = a + bytes;
        return ws + a;
    };
    int* rowptr = (int*)alloc((size_t)(N_ + 1) * 4);
    int* cursor = (int*)alloc((size_t)N_ * 4);
    int* deg    = (int*)alloc((size_t)N_ * 4);
    int* part   = (int*)alloc((size_t)(nchunks + 1) * 4);
    int* csr    = (int*)alloc((size_t)E_ * 4);
    float* s1s  = (float*)alloc((size_t)N_ * 4 * 4);
    float* s1d  = (float*)alloc((size_t)N_ * 4 * 4);
    float* Wh2  = (float*)alloc((size_t)N_ * 40 * 4);
    float* s2s  = (float*)alloc((size_t)N_ * 4);
    float* s2d  = (float*)alloc((size_t)N_ * 4);
    float* att1 = (float*)alloc((size_t)E_ * 4 * 4);   // 25.6 MB
    float* Wh1  = (float*)alloc((size_t)N_ * 256 * 4); // 102.4 MB
    size_t need = off + 256;                            // ~155 MB total

    if (ws_size < need) {
        k_sent<<<(int)((OUTEL + 255) / 256), 256, 0, stream>>>(out, OUTEL, -2.0f);
        return;
    }

    // CSR build
    k_zero<<<(N_ + 255) / 256, 256, 0, stream>>>(deg, N_);
    k_count<<<(E_ + 255) / 256, 256, 0, stream>>>(dst, deg);
    k_partial<<<nchunks, 256, 0, stream>>>(deg, part);
    k_scan_part<<<1, 64, 0, stream>>>(part, nchunks, rowptr);
    k_scan_final<<<nchunks, 256, 0, stream>>>(deg, part, rowptr, cursor);
    k_fill<<<(E_ + 255) / 256, 256, 0, stream>>>(src, dst, cursor, csr);

    // layer 1 (s1 fused into gemm1)
    dim3 g1((N_ + 63) / 64, 4);
    k_gemm1<<<g1, 256, 0, stream>>>(h, Whd, ah, Wh1, s1s, s1d);
    k_att1<<<N_, 256, 0, stream>>>(rowptr, csr, s1s, s1d, att1);

    // fused aggregate + ELU + gemm2 + s2 scores (persistent blocks)
    k_agg1g<<<AGG_BLOCKS, 512, 0, stream>>>(rowptr, csr, att1, Wh1, Wo, ao, Wh2, s2s, s2d);

    // layer 2 (att2 fused into aggregate)
    k_l2<<<N_, 64, 0, stream>>>(rowptr, csr, s2s, s2d, Wh2, out);
}

// Round 3
// 905.903 us; speedup vs baseline: 1.3304x; 1.0659x over previous
//
#include <hip/hip_runtime.h>

// GAT: N=100000 E=1600000 NFEAT=256 NHID=64 NHEADS=4 NCLASS=40 (hardcoded dims).
// r11 (965us): agg1g 248us (58% occ, VALU 54%); ~715us in sub-top-5 kernels:
// gemm1 ~145 (vector f32), att1 ~120 (16/64 lanes), l2 ~180 (3 passes).
// r12: gemm1 -> MFMA bf16-split (3-term, err ~2^-15), LDS-free, B pre-split/
// transposed by k_prepB, s1 folded in as 8 extra B-columns (wa = W@a);
// att1 -> (edge,head) lane layout, 4 nodes/block; l2 -> fused sum+agg pass;
// agg1g: bounds checks dropped (csr valid by construction).

#define ALPHA 0.2f
constexpr int N_ = 100000;
constexpr int E_ = 1600000;
constexpr long OUTEL = (long)N_ * 40;

typedef __bf16 bf16x8 __attribute__((ext_vector_type(8)));
typedef float f32x4 __attribute__((ext_vector_type(4)));

__global__ void k_sent(float* out, long n, float v) {
    long i = blockIdx.x * 256L + threadIdx.x;
    if (i < n) out[i] = v;
}

// ---------------- CSR build ----------------

__global__ void k_zero(int* p, int n) {
    int i = blockIdx.x * 256 + threadIdx.x;
    if (i < n) p[i] = 0;
}

__global__ void k_count(const int* __restrict__ dst, int* __restrict__ deg) {
    int e = blockIdx.x * 256 + threadIdx.x;
    if (e < E_) {
        int d = dst[e];
        if ((unsigned)d < (unsigned)N_) atomicAdd(&deg[d], 1);
    }
}

__global__ void k_partial(const int* __restrict__ deg, int* __restrict__ part) {
    __shared__ int sd[256];
    int b = blockIdx.x, t = threadIdx.x;
    int base = b * 1024;
    int s = 0;
    for (int i = 0; i < 4; i++) {
        int idx = base + t * 4 + i;
        if (idx < N_) s += deg[idx];
    }
    sd[t] = s;
    __syncthreads();
    for (int o = 128; o; o >>= 1) {
        if (t < o) sd[t] += sd[t + o];
        __syncthreads();
    }
    if (t == 0) part[b] = sd[0];
}

__global__ void k_scan_part(int* part, int nchunks, int* rowptr) {
    if (threadIdx.x == 0 && blockIdx.x == 0) {
        int run = 0;
        for (int b = 0; b < nchunks; b++) {
            int v = part[b];
            part[b] = run;
            run += v;
        }
        rowptr[N_] = run;
    }
}

__global__ void k_scan_final(const int* __restrict__ deg, const int* __restrict__ part,
                             int* __restrict__ rowptr, int* __restrict__ cursor) {
    __shared__ int sd[256];
    int b = blockIdx.x, t = threadIdx.x;
    int base = b * 1024;
    int v[4];
    int s = 0;
    for (int i = 0; i < 4; i++) {
        int idx = base + t * 4 + i;
        v[i] = (idx < N_) ? deg[idx] : 0;
        s += v[i];
    }
    sd[t] = s;
    __syncthreads();
    for (int o = 1; o < 256; o <<= 1) {
        int add = (t >= o) ? sd[t - o] : 0;
        __syncthreads();
        sd[t] += add;
        __syncthreads();
    }
    int off0 = part[b] + (sd[t] - s);
    for (int i = 0; i < 4; i++) {
        int idx = base + t * 4 + i;
        if (idx < N_) {
            rowptr[idx] = off0;
            cursor[idx] = off0;
            off0 += v[i];
        }
    }
}

__global__ void k_fill(const int* __restrict__ src, const int* __restrict__ dst,
                       int* __restrict__ cursor, int* __restrict__ csr) {
    int e = blockIdx.x * 256 + threadIdx.x;
    if (e < E_) {
        int d = dst[e];
        if ((unsigned)d < (unsigned)N_) {
            int p = atomicAdd(&cursor[d], 1);
            if ((unsigned)p < (unsigned)E_) csr[p] = src[e];
        }
    }
}

// ---------------- B prep: transpose + bf16 hi/lo split + wa columns ----------------
// Btc[kc][c][kk] (kc=K/32 chunk, c=col 0..271, kk=k within chunk) in bf16.
// cols 0..255 = Wcat[k][c] (head = c>>6); 256..259 = wa_s[head][k]; 260..263 = wa_d; 264..271 = 0.

__global__ __launch_bounds__(320) void k_prepB(const float* __restrict__ Whd,
                                               const float* __restrict__ ah,
                                               __bf16* __restrict__ Bh, __bf16* __restrict__ Bl) {
    int k = blockIdx.x;      // 0..255
    int c = threadIdx.x;     // 0..319
    if (c >= 272) return;
    float v = 0.f;
    if (c < 256) {
        v = Whd[(c >> 6) * 16384 + k * 64 + (c & 63)];
    } else if (c < 264) {
        int hh = (c - 256) & 3;
        int isd = (c >= 260) ? 64 : 0;
        const float* wp = Whd + hh * 16384 + k * 64;
        const float* ap = ah + hh * 128 + isd;
        float s = 0.f;
        for (int j = 0; j < 64; j++) s += wp[j] * ap[j];
        v = s;
    }
    __bf16 hi = (__bf16)v;
    __bf16 lo = (__bf16)(v - (float)hi);
    size_t idx = ((size_t)(k >> 5) * 272 + c) * 32 + (k & 31);
    Bh[idx] = hi;
    Bl[idx] = lo;
}

// ---------------- GEMM1 via MFMA 16x16x32 bf16, split-precision (3 terms).
// Block = 64 rows, 4 waves (16 rows each), 17 col-tiles (256 Wh1 cols + s1s/s1d).
// A: h rows converted f32->bf16 hi/lo in regs (each row owned by one wave).
// B: from Btc in L2 (no LDS). err ~2^-15 relative vs f32.

__global__ __launch_bounds__(256) void k_gemm1m(const float* __restrict__ h,
                                                const __bf16* __restrict__ Bh,
                                                const __bf16* __restrict__ Bl,
                                                float* __restrict__ Wh1,
                                                float* __restrict__ s1s,
                                                float* __restrict__ s1d) {
    int t = threadIdx.x;
    int wv = t >> 6, l = t & 63;
    int l15 = l & 15, lg = l >> 4;
    int rowA = blockIdx.x * 64 + wv * 16 + l15;
    bool rok = rowA < N_;
    const float* hp = h + (size_t)rowA * 256 + lg * 8;

    f32x4 acc[17];
#pragma unroll
    for (int i = 0; i < 17; i++) acc[i] = (f32x4){0.f, 0.f, 0.f, 0.f};

    for (int kc = 0; kc < 8; kc++) {
        float va[8] = {0.f, 0.f, 0.f, 0.f, 0.f, 0.f, 0.f, 0.f};
        if (rok) {
            float4 p = *(const float4*)(hp + kc * 32);
            float4 q = *(const float4*)(hp + kc * 32 + 4);
            va[0] = p.x; va[1] = p.y; va[2] = p.z; va[3] = p.w;
            va[4] = q.x; va[5] = q.y; va[6] = q.z; va[7] = q.w;
        }
        bf16x8 ahi, alo;
#pragma unroll
        for (int j = 0; j < 8; j++) {
            __bf16 hi = (__bf16)va[j];
            ahi[j] = hi;
            alo[j] = (__bf16)(va[j] - (float)hi);
        }
        const __bf16* bph = Bh + ((size_t)kc * 272 + l15) * 32 + lg * 8;
        const __bf16* bpl = Bl + ((size_t)kc * 272 + l15) * 32 + lg * 8;
#pragma unroll
        for (int tt = 0; tt < 17; tt++) {
            bf16x8 bh = *(const bf16x8*)(bph + tt * 512);
            bf16x8 bl = *(const bf16x8*)(bpl + tt * 512);
            acc[tt] = __builtin_amdgcn_mfma_f32_16x16x32_bf16(ahi, bh, acc[tt], 0, 0, 0);
            acc[tt] = __builtin_amdgcn_mfma_f32_16x16x32_bf16(alo, bh, acc[tt], 0, 0, 0);
            acc[tt] = __builtin_amdgcn_mfma_f32_16x16x32_bf16(ahi, bl, acc[tt], 0, 0, 0);
        }
    }

    // epilogue: D layout col = lane&15, row = (lane>>4)*4 + reg
    int rowD0 = blockIdx.x * 64 + wv * 16 + lg * 4;
#pragma unroll
    for (int tt = 0; tt < 16; tt++) {
#pragma unroll
        for (int r = 0; r < 4; r++) {
            int orow = rowD0 + r;
            if (orow < N_) Wh1[(size_t)orow * 256 + tt * 16 + l15] = acc[tt][r];
        }
    }
#pragma unroll
    for (int r = 0; r < 4; r++) {
        int orow = rowD0 + r;
        if (orow < N_) {
            if (l15 < 4) s1s[orow * 4 + l15] = acc[16][r];
            else if (l15 < 8) s1d[orow * 4 + (l15 - 4)] = acc[16][r];
        }
    }
}

// ---------------- att1: 1 wave/node, lane = (edge i = l>>2, head = l&3) ----------------
// 4 nodes/block (grid 25000). s1s loads: 4 lanes/edge read 16B contiguous.
// att1 writes fully coalesced (lane l writes att1[(base+ib)*4 + l]).

__global__ __launch_bounds__(256) void k_att1(const int* __restrict__ rowptr, const int* __restrict__ csr,
                                              const float* __restrict__ s1s, const float* __restrict__ s1d,
                                              float* __restrict__ att1) {
    int t = threadIdx.x;
    int wv = t >> 6, l = t & 63;
    int n = blockIdx.x * 4 + wv;
    int base = rowptr[n], deg = rowptr[n + 1] - base;
    int i = l >> 2, hh = l & 3;
    float sdw = s1d[n * 4 + hh];

    float mx = -INFINITY;
    for (int ib = 0; ib < deg; ib += 16) {
        int e = ib + i;
        if (e < deg) {
            int s = csr[base + e];
            float v = s1s[s * 4 + hh] + sdw;
            v = v > 0.f ? v : ALPHA * v;
            mx = fmaxf(mx, v);
        }
    }
    for (int o = 4; o < 64; o <<= 1) mx = fmaxf(mx, __shfl_xor(mx, o));
    float sm = 0.f;
    for (int ib = 0; ib < deg; ib += 16) {
        int e = ib + i;
        if (e < deg) {
            int s = csr[base + e];
            float v = s1s[s * 4 + hh] + sdw;
            v = v > 0.f ? v : ALPHA * v;
            sm += expf(v - mx);
        }
    }
    for (int o = 4; o < 64; o <<= 1) sm += __shfl_xor(sm, o);
    float inv = (deg > 0) ? 1.f / sm : 0.f;
    for (int ib = 0; ib < deg; ib += 16) {
        int e = ib + i;
        if (e < deg) {
            int s = csr[base + e];
            float v = s1s[s * 4 + hh] + sdw;
            v = v > 0.f ? v : ALPHA * v;
            att1[(size_t)(base + e) * 4 + hh] = expf(v - mx) * inv;
        }
    }
}

// ---------------- layer-1 aggregate + ELU + GEMM2 + s2 scores, fused, PERSISTENT.
// 768 blocks (3/CU, LDS-capped), 8 waves/block, Wo staged in LDS once/block.
// Gather: 4-edge unroll, float4. csr values valid by construction (no clamps).

constexpr int AGG_BLOCKS = 768;
constexpr int NODES_PER_SWEEP = AGG_BLOCKS * 8;

__global__ __launch_bounds__(512) void k_agg1g(const int* __restrict__ rowptr, const int* __restrict__ csr,
                                               const float* __restrict__ att1, const float* __restrict__ Wh1,
                                               const float* __restrict__ Wo, const float* __restrict__ ao,
                                               float* __restrict__ Wh2,
                                               float* __restrict__ s2s, float* __restrict__ s2d) {
    __shared__ float WoS[256 * 40];
    __shared__ float xs[8][256];
    int t = threadIdx.x;
#pragma unroll
    for (int u = 0; u < 5; u++) {
        int idx = (u * 512 + t) * 4;
        *(float4*)(&WoS[idx]) = *(const float4*)(&Wo[idx]);
    }
    __syncthreads();

    int w = t >> 6, lane = t & 63;
    int f = lane << 2;
    int hw = lane >> 4;
    float a1 = (lane < 40) ? ao[lane] : 0.f;
    float a2 = (lane < 40) ? ao[40 + lane] : 0.f;

    for (int n = blockIdx.x * 8 + w; n < N_; n += NODES_PER_SWEEP) {
        int base = rowptr[n], deg = rowptr[n + 1] - base;

        float4 acc = make_float4(0.f, 0.f, 0.f, 0.f);
        int i = 0;
        for (; i + 3 < deg; i += 4) {
            int b0 = base + i;
            int s0 = csr[b0], s1 = csr[b0 + 1], s2 = csr[b0 + 2], s3 = csr[b0 + 3];
            float at0 = att1[(size_t)b0 * 4 + hw];
            float at1 = att1[(size_t)(b0 + 1) * 4 + hw];
            float at2 = att1[(size_t)(b0 + 2) * 4 + hw];
            float at3 = att1[(size_t)(b0 + 3) * 4 + hw];
            float4 v0 = *(const float4*)(Wh1 + (size_t)s0 * 256 + f);
            float4 v1 = *(const float4*)(Wh1 + (size_t)s1 * 256 + f);
            float4 v2 = *(const float4*)(Wh1 + (size_t)s2 * 256 + f);
            float4 v3 = *(const float4*)(Wh1 + (size_t)s3 * 256 + f);
            acc.x += at0 * v0.x + at1 * v1.x + at2 * v2.x + at3 * v3.x;
            acc.y += at0 * v0.y + at1 * v1.y + at2 * v2.y + at3 * v3.y;
            acc.z += at0 * v0.z + at1 * v1.z + at2 * v2.z + at3 * v3.z;
            acc.w += at0 * v0.w + at1 * v1.w + at2 * v2.w + at3 * v3.w;
        }
        for (; i < deg; i++) {
            int s0 = csr[base + i];
            float at0 = att1[(size_t)(base + i) * 4 + hw];
            float4 v0 = *(const float4*)(Wh1 + (size_t)s0 * 256 + f);
            acc.x += at0 * v0.x;
            acc.y += at0 * v0.y;
            acc.z += at0 * v0.z;
            acc.w += at0 * v0.w;
        }
        acc.x = acc.x > 0.f ? acc.x : (expf(acc.x) - 1.f);
        acc.y = acc.y > 0.f ? acc.y : (expf(acc.y) - 1.f);
        acc.z = acc.z > 0.f ? acc.z : (expf(acc.z) - 1.f);
        acc.w = acc.w > 0.f ? acc.w : (expf(acc.w) - 1.f);
        *(float4*)(&xs[w][f]) = acc;
        // wave-private LDS RAW: compiler inserts lgkmcnt wait; no barrier needed.

        float o = 0.f;
        if (lane < 40) {
            for (int k = 0; k < 256; k += 4) {
                float4 xk = *(const float4*)(&xs[w][k]);
                o += xk.x * WoS[k * 40 + lane] + xk.y * WoS[(k + 1) * 40 + lane] +
                     xk.z * WoS[(k + 2) * 40 + lane] + xk.w * WoS[(k + 3) * 40 + lane];
            }
            Wh2[(size_t)n * 40 + lane] = o;
        }
        float r1 = o * a1, r2 = o * a2;
        for (int off = 32; off; off >>= 1) {
            r1 += __shfl_xor(r1, off);
            r2 += __shfl_xor(r2, off);
        }
        if (lane == 0) {
            s2s[n] = r1;
            s2d[n] = r2;
        }
    }
}

// ---------------- layer-2: att2 inline; sum pass FUSED into aggregate pass.
// 1 wave/node, 4 nodes/block (grid 25000). Denominator accumulated redundantly
// per lane (broadcast operands) -> no shuffle for the sum.

__global__ __launch_bounds__(256) void k_l2(const int* __restrict__ rowptr, const int* __restrict__ csr,
                                            const float* __restrict__ s2s, const float* __restrict__ s2d,
                                            const float* __restrict__ Wh2, float* __restrict__ out) {
    int t = threadIdx.x;
    int wv = t >> 6, lane = t & 63;
    int n = blockIdx.x * 4 + wv;
    int base = rowptr[n], deg = rowptr[n + 1] - base;
    float sdw = s2d[n];

    float mx = -INFINITY;
    for (int i = lane; i < deg; i += 64) {
        int s = csr[base + i];
        float e = s2s[s] + sdw;
        e = e > 0.f ? e : ALPHA * e;
        mx = fmaxf(mx, e);
    }
    for (int o = 32; o; o >>= 1) mx = fmaxf(mx, __shfl_xor(mx, o));

    float acc0 = 0.f, acc1 = 0.f, sm0 = 0.f, sm1 = 0.f;
    int i = 0;
    for (; i + 1 < deg; i += 2) {
        int s0 = csr[base + i], s1 = csr[base + i + 1];
        float e0 = s2s[s0] + sdw;
        float e1 = s2s[s1] + sdw;
        e0 = e0 > 0.f ? e0 : ALPHA * e0;
        e1 = e1 > 0.f ? e1 : ALPHA * e1;
        float a0 = expf(e0 - mx);
        float a1 = expf(e1 - mx);
        sm0 += a0; sm1 += a1;
        if (lane < 40) {
            acc0 += a0 * Wh2[(size_t)s0 * 40 + lane];
            acc1 += a1 * Wh2[(size_t)s1 * 40 + lane];
        }
    }
    if (i < deg) {
        int s0 = csr[base + i];
        float e0 = s2s[s0] + sdw;
        e0 = e0 > 0.f ? e0 : ALPHA * e0;
        float a0 = expf(e0 - mx);
        sm0 += a0;
        if (lane < 40) acc0 += a0 * Wh2[(size_t)s0 * 40 + lane];
    }
    float inv = (deg > 0) ? 1.f / (sm0 + sm1) : 0.f;
    float acc = (acc0 + acc1) * inv;

    float v = (lane < 40) ? acc : -INFINITY;
    float mv = v;
    for (int o = 32; o; o >>= 1) mv = fmaxf(mv, __shfl_xor(mv, o));
    float ex = (lane < 40) ? expf(acc - mv) : 0.f;
    float se = ex;
    for (int o = 32; o; o >>= 1) se += __shfl_xor(se, o);
    if (lane < 40) out[(size_t)n * 40 + lane] = acc - mv - logf(se);
}

// ---------------- host ----------------

extern "C" void kernel_launch(void* const* d_in, const int* in_sizes, int n_in,
                              void* d_out, int out_size, void* d_ws, size_t ws_size,
                              hipStream_t stream) {
    const float* h   = (const float*)d_in[0];
    const int*   ei  = (const int*)d_in[1];
    const float* Whd = (const float*)d_in[2];
    const float* ah  = (const float*)d_in[3];
    const float* Wo  = (const float*)d_in[4];
    const float* ao  = (const float*)d_in[5];
    float* out = (float*)d_out;

    const int* src = ei;
    const int* dst = ei + E_;
    const int nchunks = (N_ + 1023) / 1024;

    char* ws = (char*)d_ws;
    size_t off = 0;
    auto alloc = [&](size_t bytes) -> char* {
        size_t a = (off + 255) & ~(size_t)255;
        off = a + bytes;
        return ws + a;
    };
    int* rowptr = (int*)alloc((size_t)(N_ + 1) * 4);
    int* cursor = (int*)alloc((size_t)N_ * 4);
    int* deg    = (int*)alloc((size_t)N_ * 4);
    int* part   = (int*)alloc((size_t)(nchunks + 1) * 4);
    int* csr    = (int*)alloc((size_t)E_ * 4);
    float* s1s  = (float*)alloc((size_t)N_ * 4 * 4);
    float* s1d  = (float*)alloc((size_t)N_ * 4 * 4);
    float* Wh2  = (float*)alloc((size_t)N_ * 40 * 4);
    float* s2s  = (float*)alloc((size_t)N_ * 4);
    float* s2d  = (float*)alloc((size_t)N_ * 4);
    __bf16* Bh  = (__bf16*)alloc((size_t)8 * 272 * 32 * 2);   // 136 KB
    __bf16* Bl  = (__bf16*)alloc((size_t)8 * 272 * 32 * 2);
    float* att1 = (float*)alloc((size_t)E_ * 4 * 4);   // 25.6 MB
    float* Wh1  = (float*)alloc((size_t)N_ * 256 * 4); // 102.4 MB
    size_t need = off + 256;                            // ~155 MB total

    if (ws_size < need) {
        k_sent<<<(int)((OUTEL + 255) / 256), 256, 0, stream>>>(out, OUTEL, -2.0f);
        return;
    }

    // B prep (independent of CSR)
    k_prepB<<<256, 320, 0, stream>>>(Whd, ah, Bh, Bl);

    // CSR build
    k_zero<<<(N_ + 255) / 256, 256, 0, stream>>>(deg, N_);
    k_count<<<(E_ + 255) / 256, 256, 0, stream>>>(dst, deg);
    k_partial<<<nchunks, 256, 0, stream>>>(deg, part);
    k_scan_part<<<1, 64, 0, stream>>>(part, nchunks, rowptr);
    k_scan_final<<<nchunks, 256, 0, stream>>>(deg, part, rowptr, cursor);
    k_fill<<<(E_ + 255) / 256, 256, 0, stream>>>(src, dst, cursor, csr);

    // layer 1: MFMA GEMM (Wh1 + s1 scores in one shot)
    k_gemm1m<<<(N_ + 63) / 64, 256, 0, stream>>>(h, Bh, Bl, Wh1, s1s, s1d);
    k_att1<<<N_ / 4, 256, 0, stream>>>(rowptr, csr, s1s, s1d, att1);

    // fused aggregate + ELU + gemm2 + s2 scores (persistent blocks)
    k_agg1g<<<AGG_BLOCKS, 512, 0, stream>>>(rowptr, csr, att1, Wh1, Wo, ao, Wh2, s2s, s2d);

    // layer 2 (att2 + softmax-denominator fused into aggregate)
    k_l2<<<N_ / 4, 256, 0, stream>>>(rowptr, csr, s2s, s2d, Wh2, out);
}